// Round 12
// baseline (188.771 us; speedup 1.0000x reference)
//
#include <hip/hip_runtime.h>
#include <hip/hip_bf16.h>
#include <math.h>
#include <string.h>

#define CDIM 64
#define LDSW 72   // row stride in bf16 elems (144 B): b128 frag reads conflict-free (stride 36 dw)
#define DEG  5    // Chebyshev tail on [1,7.5] ~5.6e-3; Paterson-Stockmeyer s=2 -> 3 matmuls

struct Coefs { float a[DEG + 1]; float cc; float inv_h; };

typedef __attribute__((ext_vector_type(8)))  short short8;      // 8 bf16 = 4 VGPRs (MFMA A/B frag)
typedef __attribute__((ext_vector_type(16))) float floatx16;    // MFMA C/D
typedef __attribute__((ext_vector_type(4)))  float floatx4;     // packed global I/O
typedef __attribute__((ext_vector_type(4)))  unsigned short ushort4v;  // packed LDS I/O

// f32 -> bf16 via HW convert (RNE); compiler pairs into v_cvt_pk_bf16_f32.
// (R11 verified: VALUBusy 25.5 -> 15.2% vs the 4-op bit-trick.)
__device__ __forceinline__ unsigned short f2bf_rn(float x) {
  const __hip_bfloat16 b = __float2bfloat16(x);
  return __builtin_bit_cast(unsigned short, b);
}
__device__ __forceinline__ float bf2f(unsigned short s) {
  return __builtin_bit_cast(float, ((unsigned)s) << 16);
}

struct Frags  { short8 h[4]; short8 l[4]; };   // hi+lo fragments = 32 VGPRs
struct FragsH { short8 h[4]; };                // hi-only fragments = 16 VGPRs

__device__ __forceinline__ void load_frags(const unsigned short* __restrict__ Ph,
                                           const unsigned short* __restrict__ Pl,
                                           int row, int ko, Frags* f) {
#pragma unroll
  for (int kk = 0; kk < 4; ++kk) {
    f->h[kk] = *(const short8*)(Ph + row * LDSW + kk * 16 + ko);
    f->l[kk] = *(const short8*)(Pl + row * LDSW + kk * 16 + ko);
  }
}

__device__ __forceinline__ void load_frags_h(const unsigned short* __restrict__ Ph,
                                             int row, int ko, FragsH* f) {
#pragma unroll
  for (int kk = 0; kk < 4; ++kk)
    f->h[kk] = *(const short8*)(Ph + row * LDSW + kk * 16 + ko);
}

// Single-chain h*h 32x32 tile product (downstream matmuls: dropped l-terms
// are ~2^-9-relative, scaled by small coefficients -> ~1e-3 output error).
__device__ __forceinline__ floatx16 mm_h(const FragsH& a, const FragsH& b) {
  floatx16 c;
#pragma unroll
  for (int i = 0; i < 16; ++i) c[i] = 0.0f;
#pragma unroll
  for (int kk = 0; kk < 4; ++kk)
    c = __builtin_amdgcn_mfma_f32_32x32x16_bf16(a.h[kk], b.h[kk], c, 0, 0, 0);
  return c;
}

// ---- per-matrix phase helpers (proven R9 body, verbatim) ----

__device__ __forceinline__ void stage_one(const float* __restrict__ Xc,
                                          unsigned short* __restrict__ Ah,
                                          unsigned short* __restrict__ Al,
                                          float* __restrict__ rM1,
                                          int col, int base0, const Coefs& cf) {
#pragma unroll
  for (int q = 0; q < 4; ++q) {
    const int br = base0 + 8 * q;
    const floatx4 xv = *(const floatx4*)(Xc + br);
    ushort4v hv, lv;
#pragma unroll
    for (int j = 0; j < 4; ++j) {
      float x = xv[j];
      if (br + j == col) x -= cf.cc;
      const float t = x * cf.inv_h;
      rM1[4 * q + j] = t;
      const unsigned short hu = f2bf_rn(t);
      hv[j] = hu;
      lv[j] = f2bf_rn(t - bf2f(hu));
    }
    const int idxT = col * LDSW + br;
    *(ushort4v*)(Ah + idxT) = hv;
    *(ushort4v*)(Al + idxT) = lv;
  }
}

// mm1: M2 = M1*M1, full compensation (2 acc chains), fb slab-wise.
__device__ __forceinline__ floatx16 mm1_one(const unsigned short* __restrict__ Ah,
                                            const unsigned short* __restrict__ Al,
                                            int arow, int brow, int ko, Frags* fa) {
  load_frags(Ah, Al, arow, ko, fa);
  floatx16 c1, c2;
#pragma unroll
  for (int i = 0; i < 16; ++i) { c1[i] = 0.0f; c2[i] = 0.0f; }
#pragma unroll
  for (int kk = 0; kk < 4; ++kk) {
    const short8 fbh = *(const short8*)(Ah + brow * LDSW + kk * 16 + ko);
    const short8 fbl = *(const short8*)(Al + brow * LDSW + kk * 16 + ko);
    c1 = __builtin_amdgcn_mfma_f32_32x32x16_bf16(fa->h[kk], fbh, c1, 0, 0, 0);
    c2 = __builtin_amdgcn_mfma_f32_32x32x16_bf16(fa->h[kk], fbl, c2, 0, 0, 0);
    c2 = __builtin_amdgcn_mfma_f32_32x32x16_bf16(fa->l[kk], fbh, c2, 0, 0, 0);
  }
#pragma unroll
  for (int i = 0; i < 16; ++i) c1[i] += c2[i];
  return c1;
}

// pack 16 f32 (C-layout quads) -> bf16 RN into a transposed-packed buffer
__device__ __forceinline__ void st_quads(unsigned short* __restrict__ D,
                                         int col, int base0, const floatx16& v) {
#pragma unroll
  for (int q = 0; q < 4; ++q) {
    ushort4v hv;
#pragma unroll
    for (int j = 0; j < 4; ++j) hv[j] = f2bf_rn(v[4 * q + j]);
    *(ushort4v*)(D + col * LDSW + base0 + 8 * q) = hv;
  }
}

// R12: TWO matrices per block, lockstep phases, 256-reg budget.
// 11 rounds of counters: latency-bound (all pipes <35%), and every fix
// needing live state spilled at the 128-reg/4-wave cliff (R1/R4/R5/R10).
// Fix the budget instead: __launch_bounds__(256,2) -> 2 blocks/CU, 256
// regs/wave. Each wave carries TWO independent chains in-wave (ILP): B's
// ds_reads/VALU fill A's MFMA+lgkm stalls (separate pipes, m114). Barriers:
// 3 per 2 matrices = 1.5/matrix (was 3). Matrix concurrency/CU unchanged (4).
// OccupancyPercent will read ~25% (8 waves/CU) -- EXPECTED, not a failure.
// Audited peak (mm1): 2 x (fa 32 + c1c2 32 + rM1 16) ~ 170 << 256.
// Spill canary: symmetric FETCH/WRITE growth -> revert.
__global__ void __launch_bounds__(256, 2)
logm_kernel(const float* __restrict__ X, float* __restrict__ Y, int nmat, Coefs cf) {
  // Per matrix (all TRANSPOSED [col][row]; symmetric => same data):
  // A(hi+lo) = M1, Ch = M2, Dh = Q1.  2 x 4 x 9216 B = 73,728 B -> 2 blocks/CU.
  __shared__ __align__(16) unsigned short Ah_a[CDIM * LDSW], Al_a[CDIM * LDSW];
  __shared__ __align__(16) unsigned short Ch_a[CDIM * LDSW], Dh_a[CDIM * LDSW];
  __shared__ __align__(16) unsigned short Ah_b[CDIM * LDSW], Al_b[CDIM * LDSW];
  __shared__ __align__(16) unsigned short Ch_b[CDIM * LDSW], Dh_b[CDIM * LDSW];

  const int tid  = threadIdx.x;
  const int lane = tid & 63;
  const int w    = tid >> 6;

  const int R     = (w >> 1) * 32;
  const int Cc    = (w & 1) * 32;
  const int l31   = lane & 31;
  const int half  = lane >> 5;
  const int arow  = R + l31;
  const int brow  = Cc + l31;
  const int ko    = half * 8;
  const int col   = Cc + l31;
  const int base0 = R + 4 * half;   // quad q covers rows base0+8q .. +3
  // C/D layout: r=4q+j -> row = base0 + 8q + j, col = col  [verified m74/m101]

  const int ma = 2 * blockIdx.x;
  const int mb = ma + 1;
  const bool has_b = (mb < nmat);   // block-uniform (nmat=6400 -> always true)

  // ---- stage: both matrices (A's loads and B's loads overlap in flight) ----
  float rM1a[16], rM1b[16];
  stage_one(X + (size_t)ma * (CDIM * CDIM) + col * CDIM, Ah_a, Al_a, rM1a, col, base0, cf);
  if (has_b)
    stage_one(X + (size_t)mb * (CDIM * CDIM) + col * CDIM, Ah_b, Al_b, rM1b, col, base0, cf);
  __syncthreads();   // B1: M1(a), M1(b) published

  // ---- mm1 both: M2 = M1*M1 -> Ch; two independent MFMA/ds streams ----
  Frags fa_a, fa_b;
  floatx16 accM2a = mm1_one(Ah_a, Al_a, arow, brow, ko, &fa_a);
  floatx16 accM2b;
  if (has_b) accM2b = mm1_one(Ah_b, Al_b, arow, brow, ko, &fa_b);
  st_quads(Ch_a, col, base0, accM2a);
  if (has_b) st_quads(Ch_b, col, base0, accM2b);
  __syncthreads();   // B2: M2(a), M2(b) published; A reads retired

  // ---- mm2 both: T = M1*M2 (fa.h reused); Q1 = a5*T + a4*accM2 + a3*rM1 + a2*I -> Dh ----
  FragsH fah_a, fm2_a, fah_b, fm2_b;
#pragma unroll
  for (int kk = 0; kk < 4; ++kk) fah_a.h[kk] = fa_a.h[kk];
  load_frags_h(Ch_a, brow, ko, &fm2_a);   // M2 B-operand via symmetry; kept for mm3
  floatx16 accTa = mm_h(fah_a, fm2_a);
  floatx16 accTb;
  if (has_b) {
#pragma unroll
    for (int kk = 0; kk < 4; ++kk) fah_b.h[kk] = fa_b.h[kk];
    load_frags_h(Ch_b, brow, ko, &fm2_b);
    accTb = mm_h(fah_b, fm2_b);
  }
#pragma unroll
  for (int r = 0; r < 16; ++r) {
    accTa[r] = cf.a[5] * accTa[r] + cf.a[4] * accM2a[r] + cf.a[3] * rM1a[r];
    if (base0 + 8 * (r >> 2) + (r & 3) == col) accTa[r] += cf.a[2];
  }
  st_quads(Dh_a, col, base0, accTa);
  if (has_b) {
#pragma unroll
    for (int r = 0; r < 16; ++r) {
      accTb[r] = cf.a[5] * accTb[r] + cf.a[4] * accM2b[r] + cf.a[3] * rM1b[r];
      if (base0 + 8 * (r >> 2) + (r & 3) == col) accTb[r] += cf.a[2];
    }
    st_quads(Dh_b, col, base0, accTb);
  }
  __syncthreads();   // B3: Q1(a), Q1(b) published; Ch reads retired

  // ---- mm3 both: out = Q1*M2 + a1*rM1 + a0*I -> global (dwordx4, un-transposes) ----
  FragsH fq1_a;
  load_frags_h(Dh_a, arow, ko, &fq1_a);
  floatx16 accFa = mm_h(fq1_a, fm2_a);
  {
    float* __restrict__ Yc = Y + (size_t)ma * (CDIM * CDIM) + col * CDIM;
#pragma unroll
    for (int q = 0; q < 4; ++q) {
      const int br = base0 + 8 * q;
      floatx4 pv;
#pragma unroll
      for (int j = 0; j < 4; ++j) {
        const int r = 4 * q + j;
        float p = accFa[r] + cf.a[1] * rM1a[r];
        if (br + j == col) p += cf.a[0];
        pv[j] = p;
      }
      *(floatx4*)(Yc + br) = pv;
    }
  }
  if (has_b) {
    FragsH fq1_b;
    load_frags_h(Dh_b, arow, ko, &fq1_b);
    floatx16 accFb = mm_h(fq1_b, fm2_b);
    float* __restrict__ Yc = Y + (size_t)mb * (CDIM * CDIM) + col * CDIM;
#pragma unroll
    for (int q = 0; q < 4; ++q) {
      const int br = base0 + 8 * q;
      floatx4 pv;
#pragma unroll
      for (int j = 0; j < 4; ++j) {
        const int r = 4 * q + j;
        float p = accFb[r] + cf.a[1] * rM1b[r];
        if (br + j == col) p += cf.a[0];
        pv[j] = p;
      }
      *(floatx4*)(Yc + br) = pv;
    }
  }
}

extern "C" void kernel_launch(void* const* d_in, const int* in_sizes, int n_in,
                              void* d_out, int out_size, void* d_ws, size_t ws_size,
                              hipStream_t stream) {
  const float* X = (const float*)d_in[0];
  float* Y = (float*)d_out;
  const int nmat = in_sizes[0] / (CDIM * CDIM);

  // Chebyshev coefficients of log on [lo,hi] -> monomial basis in t=(x-cc)/hh.
  // Analytic: log(cc+hh*t) = log(A) - 2*sum_k z^k/k T_k(t),  z=(-cc+sqrt(cc^2-hh^2))/hh
  Coefs cf;
  {
    const double lo = 1.0, hi = 7.5;
    const double cc = 0.5 * (lo + hi), hh = 0.5 * (hi - lo);
    const double s  = sqrt(cc * cc - hh * hh);
    const double z  = (-cc + s) / hh;
    const double A  = 0.5 * (cc + s);
    double cheb[DEG + 1];
    cheb[0] = log(A);
    double zp = 1.0;
    for (int k = 1; k <= DEG; ++k) { zp *= z; cheb[k] = -2.0 * zp / (double)k; }
    double mono[DEG + 1], Tprev[DEG + 1], Tcur[DEG + 1];
    memset(mono, 0, sizeof(mono));
    memset(Tprev, 0, sizeof(Tprev));
    memset(Tcur, 0, sizeof(Tcur));
    Tprev[0] = 1.0; mono[0] += cheb[0];
    Tcur[1]  = 1.0; mono[1] += cheb[1];
    for (int k = 2; k <= DEG; ++k) {
      double Tn[DEG + 1];
      memset(Tn, 0, sizeof(Tn));
      for (int j = 0; j <= k; ++j) {
        double v = -Tprev[j];
        if (j > 0) v += 2.0 * Tcur[j - 1];
        Tn[j] = v;
      }
      for (int j = 0; j <= k; ++j) mono[j] += cheb[k] * Tn[j];
      for (int j = 0; j <= DEG; ++j) { Tprev[j] = Tcur[j]; Tcur[j] = Tn[j]; }
    }
    for (int i = 0; i <= DEG; ++i) cf.a[i] = (float)mono[i];
    cf.cc = (float)cc; cf.inv_h = (float)(1.0 / hh);
  }

  const int nblk = (nmat + 1) / 2;
  dim3 grid(nblk), block(256);
  hipLaunchKernelGGL(logm_kernel, grid, block, 0, stream, X, Y, nmat, cf);
}